// Round 6
// baseline (400.468 us; speedup 1.0000x reference)
//
#include <hip/hip_runtime.h>

typedef unsigned short u16;
typedef __attribute__((ext_vector_type(8))) short s16x8;
typedef __attribute__((ext_vector_type(4))) short s16x4;
typedef __attribute__((ext_vector_type(4))) float f32x4;

#define LOG2E 1.4426950408889634f

__device__ __forceinline__ u16 f2bf(float f){
  union { float f; unsigned u; } v; v.f = f;
  unsigned r = v.u + 0x7FFFu + ((v.u >> 16) & 1u);
  return (u16)(r >> 16);
}
__device__ __forceinline__ float bf2f(u16 h){
  union { unsigned u; float f; } v; v.u = ((unsigned)h) << 16;
  return v.f;
}
__device__ __forceinline__ f32x4 mfma16(s16x8 a, s16x8 b, f32x4 c){
  return __builtin_amdgcn_mfma_f32_16x16x32_bf16(a, b, c, 0, 0, 0);
}
__device__ __forceinline__ void gload16(const void* g, void* l){
  __builtin_amdgcn_global_load_lds((const __attribute__((address_space(1))) void*)g,
                                   (__attribute__((address_space(3))) void*)l, 16, 0, 0);
}
// frag-linear offset for W[k_out][c_in] consumed as MFMA B-frags
__device__ __forceinline__ int flidx(int k, int c){
  return ((k >> 4) * 16 + (c >> 5)) * 512 + ((c >> 3) & 3) * 128 + (k & 15) * 8 + (c & 7);
}

// ---------------------------------------------------------------------------
// K0prep: blocks 0..2047 weight transform (WiFL/WTi_rm PRE-SCALED by log2e);
// blocks 2048..10239 x f32 -> bf16.
// ---------------------------------------------------------------------------
__global__ __launch_bounds__(256) void k0prep(
    const float* __restrict__ W_in, const float* __restrict__ W_inter, const float* __restrict__ W_last,
    u16* __restrict__ WT_in, u16* __restrict__ WTi_rm, u16* __restrict__ WiFL, u16* __restrict__ WlFL,
    const float* __restrict__ x, u16* __restrict__ xb)
{
  if (blockIdx.x < 2048){
    const int t = blockIdx.x * 256 + threadIdx.x;
    if (t < 1024 * 512){ const int k = t >> 9, c = t & 511; WT_in[t] = f2bf(W_in[c * 1536 + k]); }
    if (t < 512 * 512){
      const int k = t >> 9, c = t & 511;
      const int fl = flidx(k, c);
      const u16 wi = f2bf(W_inter[c * 512 + k] * LOG2E);   // exp2 fold
      WTi_rm[t] = wi;
      WiFL[fl]  = wi;
      WlFL[fl]  = f2bf(W_last[c * 512 + k]);
    }
  } else {
    const int t = (blockIdx.x - 2048) * 256 + threadIdx.x;
    const f32x4* src = (const f32x4*)x + (size_t)t * 2;
    f32x4 a = src[0], b = src[1];
    alignas(16) u16 h[8];
    #pragma unroll
    for (int i = 0; i < 4; ++i){ h[i] = f2bf(a[i]); h[4 + i] = f2bf(b[i]); }
    *(s16x8*)&xb[(size_t)t * 8] = *(const s16x8*)h;
  }
}

// ---------------------------------------------------------------------------
// K0b: WviFL = W_v @ (W_inter*log2e)  (frag-linear, scaled via WTi_rm);
// b_vi = (b_inter + b_v@W_inter)*log2e ; b_abs = b_inter*log2e.
// ---------------------------------------------------------------------------
__global__ __launch_bounds__(256) void k0b_wvi(
    const float* __restrict__ W_in, const float* __restrict__ W_inter,
    const u16* __restrict__ WTi_rm, const float* __restrict__ b_in, const float* __restrict__ b_inter,
    u16* __restrict__ WviFL, float* __restrict__ b_vi, float* __restrict__ b_abs)
{
  __shared__ u16 A_lds[64][72];
  if (blockIdx.x >= 16){
    float* r = (float*)&A_lds[0][0];
    const int k = (blockIdx.x - 16) * 64 + (threadIdx.x & 63);
    const int pt = threadIdx.x >> 6;
    float s = 0.f;
    #pragma unroll 4
    for (int c = pt * 128; c < pt * 128 + 128; ++c)
      s += b_in[1024 + c] * W_inter[c * 512 + k];
    r[pt * 64 + (threadIdx.x & 63)] = s;
    __syncthreads();
    if (pt == 0){
      const int kk = threadIdx.x;
      b_vi[k]  = (b_inter[k] + r[kk] + r[64 + kk] + r[128 + kk] + r[192 + kk]) * LOG2E;
      b_abs[k] = b_inter[k] * LOG2E;
    }
    return;
  }
  const int kt = blockIdx.x & 1;
  const int m0 = (blockIdx.x >> 1) * 64;
  const int tid = threadIdx.x;
  const int w = tid >> 6, l = tid & 63;
  const int l15 = l & 15, lg = l >> 4;
  const int kbase = kt * 256 + w * 64;
  f32x4 acc[4][4] = {};
  const int sr = tid >> 2, sc = (tid & 3) * 16;
  for (int c0 = 0; c0 < 512; c0 += 64){
    __syncthreads();
    {
      const f32x4* src = (const f32x4*)(W_in + (size_t)(m0 + sr) * 1536 + 1024 + c0 + sc);
      f32x4 a0 = src[0], a1 = src[1], a2 = src[2], a3 = src[3];
      alignas(16) u16 h[16];
      #pragma unroll
      for (int i = 0; i < 4; ++i){ h[i] = f2bf(a0[i]); h[4+i] = f2bf(a1[i]); h[8+i] = f2bf(a2[i]); h[12+i] = f2bf(a3[i]); }
      *(s16x8*)&A_lds[sr][sc]     = *(const s16x8*)&h[0];
      *(s16x8*)&A_lds[sr][sc + 8] = *(const s16x8*)&h[8];
    }
    __syncthreads();
    #pragma unroll
    for (int kk = 0; kk < 2; ++kk){
      s16x8 af[4];
      #pragma unroll
      for (int m = 0; m < 4; ++m)
        af[m] = *(const s16x8*)&A_lds[m * 16 + l15][kk * 32 + lg * 8];
      #pragma unroll
      for (int kc = 0; kc < 4; ++kc){
        s16x8 bf = *(const s16x8*)&WTi_rm[(size_t)(kbase + kc * 16 + l15) * 512 + c0 + kk * 32 + lg * 8];
        #pragma unroll
        for (int m = 0; m < 4; ++m) acc[m][kc] = mfma16(af[m], bf, acc[m][kc]);
      }
    }
  }
  #pragma unroll
  for (int kc = 0; kc < 4; ++kc){
    const int k = kbase + kc * 16 + l15;
    #pragma unroll
    for (int m = 0; m < 4; ++m){
      const int cin = m0 + m * 16 + lg * 4;
      uint2 pk;
      pk.x = (unsigned)f2bf(acc[m][kc][0]) | ((unsigned)f2bf(acc[m][kc][1]) << 16);
      pk.y = (unsigned)f2bf(acc[m][kc][2]) | ((unsigned)f2bf(acc[m][kc][3]) << 16);
      *(uint2*)&WviFL[flidx(k, cin)] = pk;
    }
  }
}

// ---------------------------------------------------------------------------
// K1: Q,K = xb @ WT_in[0:1024] + b_in.  128x128 tile, BK=64, 4 waves.
// ---------------------------------------------------------------------------
__global__ __launch_bounds__(256) void k1_qk(
    const u16* __restrict__ xb, const u16* __restrict__ WT_in, const float* __restrict__ b_in,
    u16* __restrict__ Qp, u16* __restrict__ Kp)
{
  __shared__ __align__(16) u16 As[128 * 64];
  __shared__ __align__(16) u16 Bs[128 * 64];
  const int t = threadIdx.x;
  const int w = t >> 6, l = t & 63;
  const int l15 = l & 15, lg = l >> 4;
  const int wr = w >> 1, wc = w & 1;
  const size_t Mbase = (size_t)blockIdx.y * 128;
  const int Nbase = blockIdx.x * 128;

  f32x4 acc[4][4] = {};
  for (int c0 = 0; c0 < 512; c0 += 64){
    __syncthreads();
    #pragma unroll
    for (int it = 0; it < 4; ++it){
      const int g = it * 256 + t;
      const int row = g >> 3, cc = g & 7;
      const int sc = (cc ^ (row & 7)) * 8;
      gload16(&xb[(Mbase + row) * 512 + c0 + sc], &As[g * 8]);
    }
    #pragma unroll
    for (int it = 0; it < 4; ++it){
      const int g = it * 256 + t;
      const int row = g >> 3, cc = g & 7;
      const int sc = (cc ^ (row & 7)) * 8;
      gload16(&WT_in[(size_t)(Nbase + row) * 512 + c0 + sc], &Bs[g * 8]);
    }
    __syncthreads();
    #pragma unroll
    for (int kk = 0; kk < 2; ++kk){
      s16x8 af[4], bf[4];
      #pragma unroll
      for (int m = 0; m < 4; ++m){
        const int row = wr * 64 + m * 16 + l15;
        af[m] = *(const s16x8*)&As[row * 64 + ((kk * 4 + lg) ^ (row & 7)) * 8];
      }
      #pragma unroll
      for (int n = 0; n < 4; ++n){
        const int row = wc * 64 + n * 16 + l15;
        bf[n] = *(const s16x8*)&Bs[row * 64 + ((kk * 4 + lg) ^ (row & 7)) * 8];
      }
      #pragma unroll
      for (int n = 0; n < 4; ++n)
        #pragma unroll
        for (int m = 0; m < 4; ++m) acc[m][n] = mfma16(af[m], bf[n], acc[m][n]);
    }
  }
  const int b = (int)(Mbase >> 12);
  const int ploc = ((int)Mbase & 4095) + wr * 64;
  #pragma unroll
  for (int n = 0; n < 4; ++n){
    const int kglob = Nbase + wc * 64 + n * 16 + l15;
    const float bias = b_in[kglob];
    u16* dst = (kglob < 512) ? Qp : Kp;
    const int kq = kglob & 511;
    #pragma unroll
    for (int m = 0; m < 4; ++m){
      const int p = ploc + m * 16 + lg * 4;
      uint2 pk;
      pk.x = (unsigned)f2bf(acc[m][n][0] + bias) | ((unsigned)f2bf(acc[m][n][1] + bias) << 16);
      pk.y = (unsigned)f2bf(acc[m][n][2] + bias) | ((unsigned)f2bf(acc[m][n][3] + bias) << 16);
      *(uint2*)&dst[((size_t)b * 512 + kq) * 4096 + p] = pk;
    }
  }
}

// ---------------------------------------------------------------------------
// K3 (s1+s2, pooling inlined): blocks 0..255 S1 -> pos 0..1023;
// 256..511 S2 -> pos 1024..2047.  16 ch/block, LDS-staged coalesced output.
// ---------------------------------------------------------------------------
__global__ __launch_bounds__(512) void k3_scores(
    const u16* __restrict__ Qp, const u16* __restrict__ Kp, u16* __restrict__ T12)
{
  __shared__ __align__(16) u16 buf[1024 * 20];
  const bool s2 = blockIdx.x >= 256;
  const int blk = blockIdx.x & 255;
  const int b = blk >> 5, c0 = (blk & 31) * 16;
  const int w = threadIdx.x >> 6;
  const int l = threadIdx.x & 63, l15 = l & 15, lg = l >> 4;
  #pragma unroll
  for (int half = 0; half < 2; ++half){
    const int c = c0 + half * 8 + w;
    const int ci = half * 8 + w;
    const u16* Qr = Qp + ((size_t)b * 512 + c) * 4096;
    const u16* Kr = Kp + ((size_t)b * 512 + c) * 4096;
    if (!s2){
      f32x4 acc[4] = {};
      #pragma unroll
      for (int kk = 0; kk < 2; ++kk){
        float pv[8] = {};
        #pragma unroll
        for (int r = 0; r < 4; ++r){
          s16x8 v = *(const s16x8*)&Kr[(4 * l15 + r) * 64 + kk * 32 + lg * 8];
          #pragma unroll
          for (int j = 0; j < 8; ++j) pv[j] += bf2f((u16)v[j]);
        }
        alignas(16) u16 bh[8];
        #pragma unroll
        for (int j = 0; j < 8; ++j) bh[j] = f2bf(pv[j] * 0.25f);
        s16x8 bf = *(const s16x8*)bh;
        #pragma unroll
        for (int m = 0; m < 4; ++m){
          s16x8 af = *(const s16x8*)&Qr[(m * 16 + l15) * 64 + kk * 32 + lg * 8];
          acc[m] = mfma16(af, bf, acc[m]);
        }
      }
      #pragma unroll
      for (int m = 0; m < 4; ++m)
        #pragma unroll
        for (int j = 0; j < 4; ++j)
          buf[((m * 16 + lg * 4 + j) * 16 + l15) * 20 + ci] = f2bf(acc[m][j]);
    } else {
      f32x4 acc[4] = {};
      #pragma unroll
      for (int kk = 0; kk < 2; ++kk){
        float pv[8] = {};
        #pragma unroll
        for (int r = 0; r < 4; ++r){
          s16x8 v = *(const s16x8*)&Qr[(4 * l15 + r) * 64 + kk * 32 + lg * 8];
          #pragma unroll
          for (int j = 0; j < 8; ++j) pv[j] += bf2f((u16)v[j]);
        }
        alignas(16) u16 ah[8];
        #pragma unroll
        for (int j = 0; j < 8; ++j) ah[j] = f2bf(pv[j] * 0.25f);
        s16x8 af = *(const s16x8*)ah;
        #pragma unroll
        for (int nt = 0; nt < 4; ++nt){
          s16x8 bf = *(const s16x8*)&Kr[(nt * 16 + l15) * 64 + kk * 32 + lg * 8];
          acc[nt] = mfma16(af, bf, acc[nt]);
        }
      }
      #pragma unroll
      for (int nt = 0; nt < 4; ++nt)
        #pragma unroll
        for (int j = 0; j < 4; ++j)
          buf[((lg * 4 + j) * 64 + nt * 16 + l15) * 20 + ci] = f2bf(acc[nt][j]);
    }
  }
  __syncthreads();
  const int off = s2 ? 1024 : 0;
  for (int rr = (int)threadIdx.x; rr < 1024; rr += 512){
    uint2 a  = *(const uint2*)&buf[rr * 20 + 0];
    uint2 bq = *(const uint2*)&buf[rr * 20 + 4];
    uint2 cq = *(const uint2*)&buf[rr * 20 + 8];
    uint2 dq = *(const uint2*)&buf[rr * 20 + 12];
    u16* dst = &T12[((size_t)b * 2048 + off + rr) * 512 + c0];
    *(uint4*)&dst[0] = make_uint4(a.x, a.y, bq.x, bq.y);
    *(uint4*)&dst[8] = make_uint4(cq.x, cq.y, dq.x, dq.y);
  }
}

// ---------------------------------------------------------------------------
// K4 (merged V+ab): 32-pos tiles.  blocks x<128 = V (Pn=4096); x>=128 = ab
// (Pn=2048).  Grid 192x8 = 1536 = 3.0 x 512 co-resident -> no partial round.
// Parity W-prefetch (depth 2, no reg copies); widened P swizzle
// sw=((row&7)<<3)^((row&8)<<1) -> conflict-free stores, 2-way reads;
// exp2 with pre-scaled weights; 3 barriers.
// ---------------------------------------------------------------------------
__global__ __launch_bounds__(512) void k4_interlast(
    const u16* __restrict__ TV, const u16* __restrict__ Tab,
    u16* __restrict__ OV, u16* __restrict__ Oab,
    const u16* __restrict__ WviFL, const float* __restrict__ b_vi,
    const u16* __restrict__ WiFL, const float* __restrict__ b_abs,
    const u16* __restrict__ WlFL, const float* __restrict__ bl)
{
  __shared__ __align__(16) u16 smem[32 * 512];     // 32 KB: A tile, then P tile
  __shared__ __align__(16) float red2[32 * 8];     // 1 KB partial denominators
  const bool isV = blockIdx.x < 128;
  const int bx = isV ? (int)blockIdx.x : (int)blockIdx.x - 128;
  const int Pn = isV ? 4096 : 2048;
  const u16* T = isV ? TV : Tab;
  u16* O = isV ? OV : Oab;
  const u16* W1 = isV ? WviFL : WiFL;
  const float* bi = isV ? b_vi : b_abs;
  const int b = blockIdx.y;
  const int p0 = bx * 32;
  const int w = threadIdx.x >> 6, l = threadIdx.x & 63;
  const int l15 = l & 15, lg = l >> 4;
  const u16* Tb = T + (size_t)b * Pn * 512;

  #pragma unroll
  for (int it = 0; it < 4; ++it){
    const int g = it * 512 + threadIdx.x;            // 2048 granules = 32 x 64
    const int row = g >> 6, cc = g & 63;
    const int sc = ((cc & 7) ^ (row & 7)) | (cc & 56);
    gload16(&Tb[(size_t)(p0 + row) * 512 + sc * 8], &smem[g * 8]);
  }
  __syncthreads();                                   // bar1: A staged

  f32x4 acc[2][4] = {};
  {
    s16x8 bf[2][4];
    #pragma unroll
    for (int kc = 0; kc < 4; ++kc){
      bf[0][kc] = *(const s16x8*)&W1[(size_t)(((w * 4 + kc) * 16 + 0) * 64 + l) * 8];
      bf[1][kc] = *(const s16x8*)&W1[(size_t)(((w * 4 + kc) * 16 + 1) * 64 + l) * 8];
    }
    #pragma unroll
    for (int cs = 0; cs < 16; ++cs){
      s16x8 af[2];
      #pragma unroll
      for (int pr = 0; pr < 2; ++pr){
        const int row = pr * 16 + l15;
        const int gi = cs * 4 + lg;
        const int gs = ((gi & 7) ^ (row & 7)) | (gi & 56);
        af[pr] = *(const s16x8*)&smem[row * 512 + gs * 8];
      }
      #pragma unroll
      for (int kc = 0; kc < 4; ++kc)
        #pragma unroll
        for (int pr = 0; pr < 2; ++pr) acc[pr][kc] = mfma16(af[pr], bf[cs & 1][kc], acc[pr][kc]);
      if (cs < 14){
        #pragma unroll
        for (int kc = 0; kc < 4; ++kc)
          bf[cs & 1][kc] = *(const s16x8*)&W1[(size_t)(((w * 4 + kc) * 16 + cs + 2) * 64 + l) * 8];
      }
    }
  }
  __syncthreads();                                   // bar2: A dead

  #pragma unroll
  for (int kc = 0; kc < 4; ++kc){
    const float bias = bi[w * 64 + kc * 16 + l15];
    #pragma unroll
    for (int pr = 0; pr < 2; ++pr)
      #pragma unroll
      for (int j = 0; j < 4; ++j)
        acc[pr][kc][j] = __builtin_amdgcn_exp2f(acc[pr][kc][j] + bias);
  }
  #pragma unroll
  for (int pr = 0; pr < 2; ++pr)
    #pragma unroll
    for (int j = 0; j < 4; ++j){
      float s = (acc[pr][0][j] + acc[pr][1][j]) + (acc[pr][2][j] + acc[pr][3][j]);
      s += __shfl_xor(s, 1); s += __shfl_xor(s, 2);
      s += __shfl_xor(s, 4); s += __shfl_xor(s, 8);
      if (l15 == 0) red2[(pr * 16 + lg * 4 + j) * 8 + w] = s;
    }
  #pragma unroll
  for (int pr = 0; pr < 2; ++pr)
    #pragma unroll
    for (int j = 0; j < 4; ++j){
      const int row = pr * 16 + lg * 4 + j;
      const int sw = ((row & 7) << 3) ^ ((row & 8) << 1);
      #pragma unroll
      for (int kc = 0; kc < 4; ++kc)
        smem[row * 512 + ((w * 64 + kc * 16 + l15) ^ sw)] = f2bf(acc[pr][kc][j]);
    }
  __syncthreads();                                   // bar3: red + P complete

  float inv[2][4];
  {
    const f32x4* r = (const f32x4*)&red2[(l & 31) * 8];
    f32x4 r0 = r[0], r1 = r[1];
    float S = ((r0[0] + r0[1]) + (r0[2] + r0[3])) + ((r1[0] + r1[1]) + (r1[2] + r1[3]));
    #pragma unroll
    for (int pr = 0; pr < 2; ++pr)
      #pragma unroll
      for (int j = 0; j < 4; ++j)
        inv[pr][j] = 1.f / __shfl(S, pr * 16 + lg * 4 + j);
  }
  f32x4 z[2][4] = {};
  {
    const int swr = ((l15 & 7) << 3) ^ ((l15 & 8) << 1);  // row = pr*16+l15
    s16x8 bf[2][4];
    #pragma unroll
    for (int kc = 0; kc < 4; ++kc){
      bf[0][kc] = *(const s16x8*)&WlFL[(size_t)(((w * 4 + kc) * 16 + 0) * 64 + l) * 8];
      bf[1][kc] = *(const s16x8*)&WlFL[(size_t)(((w * 4 + kc) * 16 + 1) * 64 + l) * 8];
    }
    #pragma unroll
    for (int ks = 0; ks < 16; ++ks){
      const int k0 = ks * 32 + lg * 8;
      s16x8 af[2];
      #pragma unroll
      for (int pr = 0; pr < 2; ++pr)
        af[pr] = *(const s16x8*)&smem[(pr * 16 + l15) * 512 + (k0 ^ swr)];
      #pragma unroll
      for (int kc = 0; kc < 4; ++kc)
        #pragma unroll
        for (int pr = 0; pr < 2; ++pr) z[pr][kc] = mfma16(af[pr], bf[ks & 1][kc], z[pr][kc]);
      if (ks < 14){
        #pragma unroll
        for (int kc = 0; kc < 4; ++kc)
          bf[ks & 1][kc] = *(const s16x8*)&WlFL[(size_t)(((w * 4 + kc) * 16 + ks + 2) * 64 + l) * 8];
      }
    }
  }
  u16* Ob = O + (size_t)b * 512 * Pn;
  #pragma unroll
  for (int kc = 0; kc < 4; ++kc){
    const int k2 = w * 64 + kc * 16 + l15;
    const float bias = bl[k2];
    #pragma unroll
    for (int pr = 0; pr < 2; ++pr){
      uint2 pk;
      pk.x = (unsigned)f2bf(z[pr][kc][0] * inv[pr][0] + bias) | ((unsigned)f2bf(z[pr][kc][1] * inv[pr][1] + bias) << 16);
      pk.y = (unsigned)f2bf(z[pr][kc][2] * inv[pr][2] + bias) | ((unsigned)f2bf(z[pr][kc][3] * inv[pr][3] + bias) << 16);
      *(uint2*)&Ob[(size_t)k2 * Pn + p0 + pr * 16 + lg * 4] = pk;
    }
  }
}

// ---------------------------------------------------------------------------
// K56 (fused): per (b,c) wave: qKV = qK @ Vp ; out = Qk @ qKV.
// Tt stored TRANSPOSED [d][l] pad-24: 4x8B stores + 1x16B read per frag.
// ---------------------------------------------------------------------------
__global__ __launch_bounds__(256) void k56(
    const u16* __restrict__ O12, const u16* __restrict__ Vp, float* __restrict__ out)
{
  __shared__ __align__(16) u16 Vt[4][64 * 68];
  __shared__ __align__(16) u16 Tt[4][64 * 24];     // [d][l] pad-24
  const int w = threadIdx.x >> 6;
  const int W = blockIdx.x * 4 + w;
  const int b = W >> 9, c = W & 511;
  const int l = threadIdx.x & 63, l15 = l & 15, lg = l >> 4;
  const u16* base = O12 + ((size_t)b * 512 + c) * 2048;
  const u16* Qr = base;            // Qk [n][l]
  const u16* qr = base + 1024;     // qK [l][n]
  const u16* vr = Vp + ((size_t)b * 512 + c) * 4096;
  u16* vt = &Vt[w][0];
  u16* tt = &Tt[w][0];
  {
    const s16x8* src = (const s16x8*)&vr[l * 64];
    #pragma unroll
    for (int i = 0; i < 8; ++i){
      s16x8 v = src[i];
      *(s16x4*)&vt[l * 68 + i * 8]     = __builtin_shufflevector(v, v, 0, 1, 2, 3);
      *(s16x4*)&vt[l * 68 + i * 8 + 4] = __builtin_shufflevector(v, v, 4, 5, 6, 7);
    }
  }
  f32x4 acc1[4] = {};
  #pragma unroll
  for (int kk = 0; kk < 2; ++kk){
    s16x8 af = *(const s16x8*)&qr[l15 * 64 + kk * 32 + lg * 8];
    #pragma unroll
    for (int dt = 0; dt < 4; ++dt){
      alignas(16) u16 bh[8];
      #pragma unroll
      for (int j = 0; j < 8; ++j)
        bh[j] = vt[(kk * 32 + lg * 8 + j) * 68 + dt * 16 + l15];
      acc1[dt] = mfma16(af, *(const s16x8*)bh, acc1[dt]);
    }
  }
  // qKV -> Tt transposed: row d = dt*16+l15, cols l = lg*4+j (8B packed)
  #pragma unroll
  for (int dt = 0; dt < 4; ++dt){
    alignas(8) u16 hj[4];
    #pragma unroll
    for (int j = 0; j < 4; ++j) hj[j] = f2bf(acc1[dt][j]);
    *(s16x4*)&tt[(dt * 16 + l15) * 24 + lg * 4] = *(const s16x4*)hj;
  }
  s16x8 af2[4] = {};
  if (lg < 2){
    #pragma unroll
    for (int m = 0; m < 4; ++m)
      af2[m] = *(const s16x8*)&Qr[(m * 16 + l15) * 16 + lg * 8];
  }
  f32x4 acc2[4][4] = {};
  #pragma unroll
  for (int dt = 0; dt < 4; ++dt){
    s16x8 bf = {};
    if (lg < 2)
      bf = *(const s16x8*)&tt[(dt * 16 + l15) * 24 + lg * 8];   // B[l][d], 16B read
    #pragma unroll
    for (int m = 0; m < 4; ++m) acc2[m][dt] = mfma16(af2[m], bf, acc2[m][dt]);
  }
  float* ob = out + ((size_t)b * 512 + c) * 4096;
  #pragma unroll
  for (int m = 0; m < 4; ++m)
    #pragma unroll
    for (int dt = 0; dt < 4; ++dt)
      #pragma unroll
      for (int j = 0; j < 4; ++j)
        ob[(m * 16 + lg * 4 + j) * 64 + dt * 16 + l15] = acc2[m][dt][j];
}

// ---------------------------------------------------------------------------
extern "C" void kernel_launch(void* const* d_in, const int* in_sizes, int n_in,
                              void* d_out, int out_size, void* d_ws, size_t ws_size,
                              hipStream_t stream)
{
  (void)in_sizes; (void)n_in; (void)out_size; (void)ws_size;
  const float* x       = (const float*)d_in[0];
  const float* W_in    = (const float*)d_in[1];
  const float* b_in    = (const float*)d_in[2];
  const float* W_inter = (const float*)d_in[3];
  const float* b_inter = (const float*)d_in[4];
  const float* W_last  = (const float*)d_in[5];
  const float* b_last  = (const float*)d_in[6];
  float* out = (float*)d_out;

  char* ws = (char*)d_ws;
  size_t off = 0;
  auto alloc = [&](size_t bytes) -> u16* {
    u16* p = (u16*)(ws + off);
    off += (bytes + 255) & ~(size_t)255;
    return p;
  };
  u16*  WT_in  = alloc((size_t)1024 * 512 * 2);
  u16*  WTi_rm = alloc((size_t)512 * 512 * 2);
  u16*  WiFL   = alloc((size_t)512 * 512 * 2);
  u16*  WlFL   = alloc((size_t)512 * 512 * 2);
  u16*  WviFL  = alloc((size_t)512 * 512 * 2);
  float* b_vi  = (float*)alloc((size_t)512 * 4);
  float* b_abs = (float*)alloc((size_t)512 * 4);
  u16*  xb     = alloc((size_t)8 * 4096 * 512 * 2);
  u16*  Qp     = alloc((size_t)8 * 512 * 4096 * 2);
  u16*  Kp     = alloc((size_t)8 * 512 * 4096 * 2);
  u16*  T12    = alloc((size_t)8 * 2048 * 512 * 2);
  // aliases (lifetime-checked): Qp,Kp dead after k3
  u16*  Vpp    = Qp;
  u16*  O12    = Kp;

  k0prep<<<10240, 256, 0, stream>>>(W_in, W_inter, W_last, WT_in, WTi_rm, WiFL, WlFL, x, xb);
  k0b_wvi<<<24, 256, 0, stream>>>(W_in, W_inter, WTi_rm, b_in, b_inter, WviFL, b_vi, b_abs);
  k1_qk<<<dim3(8, 256), 256, 0, stream>>>(xb, WT_in, b_in, Qp, Kp);
  k3_scores<<<512, 512, 0, stream>>>(Qp, Kp, T12);
  k4_interlast<<<dim3(192, 8), 512, 0, stream>>>(xb, T12, Vpp, O12,
                                                 WviFL, b_vi, WiFL, b_abs, WlFL, b_last);
  k56<<<1024, 256, 0, stream>>>(O12, Vpp, out);
}